// Round 8
// baseline (315.161 us; speedup 1.0000x reference)
//
#include <hip/hip_runtime.h>
#include <hip/hip_bf16.h>
#include <hip/hip_fp16.h>

#define T_LEN   16000
#define NB      16
#define NTT     250         // T_LEN / 64 : plane chunk granularity & kP1/kE tiles
#define NTB     125         // T_LEN / 128: kC tiles
#define EPSV    1e-8f

typedef _Float16 f16x8 __attribute__((ext_vector_type(8)));
typedef float    f32x4 __attribute__((ext_vector_type(4)));

__device__ __forceinline__ ushort f2h(float f) {
    _Float16 h = (_Float16)f;
    return *(ushort*)&h;
}
__device__ __forceinline__ float f4c(const float4& v, int i) {
    return i == 0 ? v.x : i == 1 ? v.y : i == 2 ? v.z : v.w;
}
__device__ __forceinline__ void gld16(const ushort* g, ushort* l) {
    __builtin_amdgcn_global_load_lds(
        (const __attribute__((address_space(1))) uint*)g,
        (__attribute__((address_space(3))) uint*)l, 16, 0, 0);
}
__device__ __forceinline__ float waveRed64(float v) {
    #pragma unroll
    for (int m = 1; m <= 32; m <<= 1) v += __shfl_xor(v, m, 64);
    return v;
}
__device__ __forceinline__ float4 ntload4(const float* p) {
    f32x4 v = __builtin_nontemporal_load((const f32x4*)p);
    return make_float4(v[0], v[1], v[2], v[3]);
}

// ---------------------------------------------------------------------------
// kP1F: fused kW1 (blocks 0..255) + kP1 (blocks 256..4255).
// kP1 part: thread = (cq=tid>>2, jq=tid&3); owns channels {cq,cq+64,cq+128,
// cq+192}, t-quarters jq+4i. s/q accumulate thread-local (shfl only over 4
// lanes). LDS Hs[c][t] (pad 68) written b64; chunk-write gathers 8 c-rows.
// Plane: Xp[b][tt][kc] = 8KB chunk, 16B unit (t,u) at slot (t*8+(u^(t&7)))*8.
// ---------------------------------------------------------------------------
__global__ __launch_bounds__(256) void kP1F(
    const float* __restrict__ x, ushort* __restrict__ Xp,
    float* __restrict__ sp, float* __restrict__ qp,
    const float* __restrict__ cue,
    const float* __restrict__ f1g_w, const float* __restrict__ f1g_b,
    const float* __restrict__ f1b_w, const float* __restrict__ f1b_b,
    const float* __restrict__ cds_w,
    float* __restrict__ G1, float* __restrict__ B1, float* __restrict__ CUE2)
{
    const int bid = blockIdx.x;
    if (bid < 256) {
        // ---- kW1 body: per-channel cue GEMVs ----
        const int c = bid;
        const int lane = threadIdx.x & 63, w = threadIdx.x >> 6;
        const float4 wg0 = *(const float4*)(f1g_w + c*512 + lane*8);
        const float4 wg1 = *(const float4*)(f1g_w + c*512 + lane*8 + 4);
        const float4 wb0 = *(const float4*)(f1b_w + c*512 + lane*8);
        const float4 wb1 = *(const float4*)(f1b_w + c*512 + lane*8 + 4);
        const float4 wc0 = *(const float4*)(cds_w + c*512 + lane*8);
        const float4 wc1 = *(const float4*)(cds_w + c*512 + lane*8 + 4);
        #pragma unroll
        for (int bb = 0; bb < 4; ++bb) {
            const int b = w*4 + bb;
            const float4 u0 = *(const float4*)(cue + b*512 + lane*8);
            const float4 u1 = *(const float4*)(cue + b*512 + lane*8 + 4);
            float g = 0.f, bt = 0.f, cv = 0.f;
            #pragma unroll
            for (int i = 0; i < 4; ++i) {
                g  = fmaf(f4c(u0,i), f4c(wg0,i), g);  g  = fmaf(f4c(u1,i), f4c(wg1,i), g);
                bt = fmaf(f4c(u0,i), f4c(wb0,i), bt); bt = fmaf(f4c(u1,i), f4c(wb1,i), bt);
                cv = fmaf(f4c(u0,i), f4c(wc0,i), cv); cv = fmaf(f4c(u1,i), f4c(wc1,i), cv);
            }
            g = waveRed64(g); bt = waveRed64(bt); cv = waveRed64(cv);
            if (lane == 0) {
                G1[b*256 + c]   = fmaxf(g + f1g_b[c], 0.f) + 1.f;
                B1[b*256 + c]   = fmaxf(bt + f1b_b[c], 0.f);
                CUE2[b*256 + c] = fmaxf(cv, 0.f);
            }
        }
        return;
    }

    // ---- kP1 body ----
    const int pb = bid - 256;
    const int b = pb / NTT, tt = pb % NTT;
    const int t0 = tt * 64;
    const int tid = threadIdx.x;
    const int cq = tid >> 2, jq = tid & 3;
    __shared__ __align__(16) ushort Hs[256][68];

    #pragma unroll
    for (int cc = 0; cc < 4; ++cc) {
        const int c = cc*64 + cq;
        float s4 = 0.f, q4 = 0.f;
        #pragma unroll
        for (int i = 0; i < 4; ++i) {
            const int ts = (jq + i*4)*4;
            const float4 v = ntload4(x + ((size_t)(b*256 + c))*T_LEN + t0 + ts);
            s4 += v.x + v.y + v.z + v.w;
            q4 += v.x*v.x + v.y*v.y + v.z*v.z + v.w*v.w;
            const ushort h0 = f2h(v.x), h1 = f2h(v.y), h2 = f2h(v.z), h3 = f2h(v.w);
            uint2 pk;
            pk.x = (uint)h0 | ((uint)h1 << 16);
            pk.y = (uint)h2 | ((uint)h3 << 16);
            *(uint2*)&Hs[c][ts] = pk;
        }
        s4 += __shfl_xor(s4, 1, 4); s4 += __shfl_xor(s4, 2, 4);
        q4 += __shfl_xor(q4, 1, 4); q4 += __shfl_xor(q4, 2, 4);
        if (jq == 0) {
            sp[((size_t)b*NTT + tt)*256 + c] = s4;
            qp[((size_t)b*NTT + tt)*256 + c] = q4;
        }
    }
    __syncthreads();
    ushort* dst = Xp + ((size_t)(b*NTT + tt)*4)*4096;
    #pragma unroll
    for (int k = 0; k < 8; ++k) {
        const int d  = tid + k*256;          // unit idx 0..2047
        const int kc = d >> 9, r = d & 511;
        const int t  = r >> 3, us = r & 7;
        const int u  = us ^ (t & 7);
        const int c0 = kc*64 + u*8;
        uint4 val;
        val.x = (uint)Hs[c0+0][t] | ((uint)Hs[c0+1][t] << 16);
        val.y = (uint)Hs[c0+2][t] | ((uint)Hs[c0+3][t] << 16);
        val.z = (uint)Hs[c0+4][t] | ((uint)Hs[c0+5][t] << 16);
        val.w = (uint)Hs[c0+6][t] | ((uint)Hs[c0+7][t] << 16);
        *(uint4*)(dst + (size_t)d*8) = val;
    }
}

// ---------------------------------------------------------------------------
__device__ __forceinline__ float blockSum256(float v, float* red)
{
    #pragma unroll
    for (int off = 32; off; off >>= 1) v += __shfl_down(v, off, 64);
    __syncthreads();
    if ((threadIdx.x & 63) == 0) red[threadIdx.x >> 6] = v;
    __syncthreads();
    return red[0] + red[1] + red[2] + red[3];
}

// ---------------------------------------------------------------------------
// kBM (fused kB0 + kM2): per-batch stats chain -> a4,d4 (LDS), then
// G2/E/Msf production looping og=0..7.  grid 16 (b) x 256 thr.
// ---------------------------------------------------------------------------
__global__ __launch_bounds__(256) void kBM(
    const float* __restrict__ sp, const float* __restrict__ qp,
    const float* __restrict__ gn_a_w, const float* __restrict__ gn_a_b,
    const float* __restrict__ gn_n_w, const float* __restrict__ gn_n_b,
    const float* __restrict__ G1, const float* __restrict__ B1,
    const float* __restrict__ ln1_w, const float* __restrict__ ln1_b,
    const float* __restrict__ CUE2,
    const float* __restrict__ f2g_w, const float* __restrict__ f2g_b,
    const float* __restrict__ f2b_w, const float* __restrict__ f2b_b,
    const float* __restrict__ conv1_w,
    float* __restrict__ a4o, float* __restrict__ G2,
    float* __restrict__ E, ushort* __restrict__ Msf)
{
    const int b = blockIdx.x;
    const int c = threadIdx.x;
    __shared__ float red[4];
    __shared__ float sa4[256], sd4[256], sc2[256], sg2[16];

    float sc = 0.f, qc = 0.f;
    for (int i = 0; i < NTT; ++i) {
        sc += sp[((size_t)b*NTT + i)*256 + c];
        qc += qp[((size_t)b*NTT + i)*256 + c];
    }

    const float Ninv = 1.f / (256.f * 16000.f);
    const float Tf = 16000.f;

    float S  = blockSum256(sc, red);
    float Q  = blockSum256(qc, red);
    float mu1 = S * Ninv;
    float var1 = Q * Ninv - mu1 * mu1;
    float r1 = rsqrtf(var1 + EPSV);
    float a1 = gn_a_w[c] * r1;
    float d1 = gn_a_b[c] - mu1 * r1 * gn_a_w[c];

    float S2 = blockSum256(a1*sc + Tf*d1, red);
    float Q2 = blockSum256(a1*a1*qc + 2.f*a1*d1*sc + Tf*d1*d1, red);
    float mu2 = S2 * Ninv;
    float var2 = Q2 * Ninv - mu2 * mu2;
    float r2 = rsqrtf(var2 + EPSV);
    float wn = gn_n_w[c];
    float a2 = wn * r2 * a1;
    float d2 = wn * r2 * (d1 - mu2) + gn_n_b[c];

    const float g1 = G1[b*256 + c];
    const float b1 = B1[b*256 + c];
    float a3 = g1 * a2;
    float d3 = g1 * d2 + b1;

    float S3 = blockSum256(a3*sc + Tf*d3, red);
    float Q3 = blockSum256(a3*a3*qc + 2.f*a3*d3*sc + Tf*d3*d3, red);
    float mu3 = S3 * Ninv;
    float var3 = Q3 * Ninv - mu3 * mu3;
    float r3 = rsqrtf(var3 + EPSV);
    float w1 = ln1_w[c];
    const float a4v = w1 * r3 * a3;
    const float d4v = w1 * r3 * (d3 - mu3) + ln1_b[c];
    sa4[c] = a4v;
    sd4[c] = d4v;
    a4o[b*256 + c] = a4v;
    sc2[c] = CUE2[b*256 + c];
    __syncthreads();

    const int oi = c >> 4, l16 = c & 15;
    for (int og = 0; og < 8; ++og) {
        const int o = og*16 + oi;
        float g = 0.f, bt = 0.f, ed = 0.f;
        #pragma unroll
        for (int q = 0; q < 4; ++q) {
            const int k0 = l16*16 + q*4;
            const float4 a  = *(const float4*)(f2g_w  + o*256 + k0);
            const float4 bb = *(const float4*)(f2b_w  + o*256 + k0);
            const float4 cc = *(const float4*)(conv1_w + o*256 + k0);
            const float4 u  = *(const float4*)(&sc2[k0]);
            const float4 dd = *(const float4*)(&sd4[k0]);
            #pragma unroll
            for (int i = 0; i < 4; ++i) {
                g  = fmaf(f4c(u,i),  f4c(a,i),  g);
                bt = fmaf(f4c(u,i),  f4c(bb,i), bt);
                ed = fmaf(f4c(dd,i), f4c(cc,i), ed);
            }
        }
        #pragma unroll
        for (int m = 1; m <= 8; m <<= 1) {
            g  += __shfl_xor(g, m, 16);
            bt += __shfl_xor(bt, m, 16);
            ed += __shfl_xor(ed, m, 16);
        }
        if (l16 == 0) {
            const float G2v = fmaxf(g + f2g_b[o], 0.f) + 1.f;
            const float B2v = fmaxf(bt + f2b_b[o], 0.f);
            G2[b*128 + o] = G2v;
            E[b*128 + o]  = G2v * ed + B2v;
            sg2[oi] = G2v;
        }
        __syncthreads();
        const float av = sa4[c];
        #pragma unroll
        for (int i = 0; i < 16; ++i) {
            const int oo = og*16 + i;
            Msf[((size_t)b*128 + oo)*256 + c] = f2h(sg2[i] * conv1_w[oo*256 + c] * av);
        }
        __syncthreads();
    }
}

// ---------------------------------------------------------------------------
// Kernel C: stats GEMM z2 = M x + e.  Block 128o x 128t, 4 waves (2o x 2t).
// ---------------------------------------------------------------------------
__global__ __launch_bounds__(256) void kC_gemm(
    const ushort* __restrict__ Xp, const ushort* __restrict__ Msf,
    const float* __restrict__ E,
    float* __restrict__ s2p, float* __restrict__ q2p)
{
    const int tb = blockIdx.x, b = blockIdx.y;
    const int tid = threadIdx.x, lane = tid & 63, w = tid >> 6;
    const int wo = w >> 1, wt = w & 1;
    const int sub = lane >> 4, li = lane & 15;
    const int o0 = wo * 64;
    __shared__ __align__(16) ushort Bs[2][8192];
    __shared__ float sSp[2][128], sQp[2][128];

    const ushort* src = Xp + ((size_t)(b*NTT + 2*tb)*4)*4096;
    const ushort* mp  = Msf + (size_t)b*128*256;

    f32x4 acc[4][4];
    #pragma unroll
    for (int i = 0; i < 4; ++i)
        #pragma unroll
        for (int jx = 0; jx < 4; ++jx) acc[i][jx] = (f32x4){0.f,0.f,0.f,0.f};

    #pragma unroll
    for (int jj = 0; jj < 4; ++jj) {
        const int m = w*4 + jj;
        const int ch = m >> 3, off = (m & 7)*512;
        gld16(src + (size_t)ch*16384 + off + lane*8, &Bs[0][ch*4096 + off]);
    }
    __syncthreads();
    for (int kc = 0; kc < 4; ++kc) {
        const int buf = kc & 1;
        if (kc < 3) {
            #pragma unroll
            for (int jj = 0; jj < 4; ++jj) {
                const int m = w*4 + jj;
                const int ch = m >> 3, off = (m & 7)*512;
                gld16(src + (size_t)ch*16384 + (kc+1)*4096 + off + lane*8,
                      &Bs[buf^1][ch*4096 + off]);
            }
        }
        f16x8 bfr[4][2];
        #pragma unroll
        for (int ft = 0; ft < 4; ++ft) {
            const int tl = ft*16 + li;
            #pragma unroll
            for (int ks = 0; ks < 2; ++ks) {
                const int u = (4*ks + sub) ^ (tl & 7);
                bfr[ft][ks] = *(const f16x8*)&Bs[buf][wt*4096 + tl*64 + u*8];
            }
        }
        #pragma unroll
        for (int ks = 0; ks < 2; ++ks) {
            #pragma unroll
            for (int fo = 0; fo < 4; ++fo) {
                const f16x8 a = *(const f16x8*)(mp + (size_t)(o0 + fo*16 + li)*256 + kc*64 + ks*32 + 8*sub);
                #pragma unroll
                for (int ft = 0; ft < 4; ++ft)
                    acc[fo][ft] = __builtin_amdgcn_mfma_f32_16x16x32_f16(a, bfr[ft][ks], acc[fo][ft], 0, 0, 0);
            }
        }
        __syncthreads();
    }

    #pragma unroll
    for (int fo = 0; fo < 4; ++fo) {
        #pragma unroll
        for (int r = 0; r < 4; ++r) {
            const int o = o0 + fo*16 + sub*4 + r;
            const float ev = E[b*128 + o];
            float sv = 0.f, qv = 0.f;
            #pragma unroll
            for (int ft = 0; ft < 4; ++ft) {
                const float z = acc[fo][ft][r] + ev;
                sv += z; qv += z*z;
            }
            #pragma unroll
            for (int m = 1; m <= 8; m <<= 1) {
                sv += __shfl_xor(sv, m, 64);
                qv += __shfl_xor(qv, m, 64);
            }
            if (li == 0) { sSp[wt][o] = sv; sQp[wt][o] = qv; }
        }
    }
    __syncthreads();
    if (tid < 128) {
        s2p[((size_t)b*NTB + tb)*128 + tid] = sSp[0][tid] + sSp[1][tid];
        q2p[((size_t)b*NTB + tb)*128 + tid] = sQp[0][tid] + sQp[1][tid];
    }
}

// ---------------------------------------------------------------------------
// Kernel D2 (kD1 folded in): per (pg,b) block reduces s2p/q2p -> A2/AE (LDS),
// then F = [conv2*diag(A2*G2)*conv1]*diag(a4) (fp16), h = conv2.AE.
// ---------------------------------------------------------------------------
__global__ __launch_bounds__(256) void kD2_buildF(
    const float* __restrict__ s2p, const float* __restrict__ q2p,
    const float* __restrict__ ln2_w, const float* __restrict__ ln2_b,
    const float* __restrict__ Ev,
    const float* __restrict__ a4, const float* __restrict__ G2,
    const float* __restrict__ conv1_w, const float* __restrict__ conv2_w,
    ushort* __restrict__ Fsf, float* __restrict__ h)
{
    const int b = blockIdx.y, pg = blockIdx.x;
    const int tid = threadIdx.x;
    __shared__ float Qs[32][128];
    __shared__ float sA2[128], sAE[128];
    __shared__ float rS[2], rQ[2];

    float s = 0.f, qq = 0.f;
    if (tid < 128) {
        for (int tb = 0; tb < NTB; ++tb) {
            s  += s2p[((size_t)b*NTB + tb)*128 + tid];
            qq += q2p[((size_t)b*NTB + tb)*128 + tid];
        }
        float S = s, Q = qq;
        #pragma unroll
        for (int off = 32; off; off >>= 1) {
            S += __shfl_down(S, off, 64);
            Q += __shfl_down(Q, off, 64);
        }
        if ((tid & 63) == 0) { rS[tid >> 6] = S; rQ[tid >> 6] = Q; }
    }
    __syncthreads();
    const float N2inv = 1.f / (128.f * 16000.f);
    const float mu  = (rS[0] + rS[1]) * N2inv;
    const float var = (rQ[0] + rQ[1]) * N2inv - mu * mu;
    const float r = rsqrtf(var + EPSV);
    if (tid < 128) {
        const float a2v = ln2_w[tid] * r;
        const float d2v = ln2_b[tid] - mu * ln2_w[tid] * r;
        sA2[tid] = a2v;
        sAE[tid] = a2v * Ev[b*128 + tid] + d2v;
    }
    __syncthreads();

    #pragma unroll
    for (int k = 0; k < 16; ++k) {
        const int idx = tid + k*256;
        const int p = idx >> 7, o = idx & 127;
        Qs[p][o] = conv2_w[(pg*32 + p)*128 + o] * sA2[o] * G2[b*128 + o];
    }
    __syncthreads();
    float acc[32];
    #pragma unroll
    for (int p = 0; p < 32; ++p) acc[p] = 0.f;
    for (int o = 0; o < 128; ++o) {
        const float mv = conv1_w[o*256 + tid];
        #pragma unroll
        for (int p = 0; p < 32; ++p) acc[p] = fmaf(Qs[p][o], mv, acc[p]);
    }
    const float a = a4[b*256 + tid];
    #pragma unroll
    for (int p = 0; p < 32; ++p) {
        const size_t idx = ((size_t)b*256 + pg*32 + p)*256 + tid;
        Fsf[idx] = f2h(acc[p] * a);
    }
    if (tid < 32) {
        const int p = pg*32 + tid;
        float hv = 0.f;
        for (int o = 0; o < 128; ++o)
            hv += conv2_w[p*128 + o] * sAE[o];
        h[b*256 + p] = hv;
    }
}

// ---------------------------------------------------------------------------
// Kernel E: out = F x + h.  Block 256o x 64t, 4 waves = 4 o-strips.
// B staged via global_load_lds dbuf.  Epilogue: per-wave LDS transpose ->
// nontemporal dwordx4 stores (256B runs).
// ---------------------------------------------------------------------------
__global__ __launch_bounds__(256) void kE_gemm(
    const ushort* __restrict__ Xp, const ushort* __restrict__ Fsf,
    const float* __restrict__ h, float* __restrict__ out)
{
    const int tt = blockIdx.x, b = blockIdx.y;
    const int tid = threadIdx.x, lane = tid & 63, w = tid >> 6;
    const int sub = lane >> 4, li = lane & 15;
    const int o0 = w * 64, t0 = tt * 64;
    __shared__ __align__(16) ushort Bs[2][4096];
    __shared__ __align__(16) float Ts[4][16][68];

    const ushort* src = Xp + ((size_t)(b*NTT + tt)*4)*4096;
    const ushort* fp  = Fsf + (size_t)b*65536;

    f32x4 acc[4][4];
    #pragma unroll
    for (int i = 0; i < 4; ++i)
        #pragma unroll
        for (int jx = 0; jx < 4; ++jx) acc[i][jx] = (f32x4){0.f,0.f,0.f,0.f};

    #pragma unroll
    for (int jj = 0; jj < 2; ++jj) {
        const int m = w*2 + jj;
        gld16(src + m*512 + lane*8, &Bs[0][m*512]);
    }
    __syncthreads();
    for (int kc = 0; kc < 4; ++kc) {
        const int buf = kc & 1;
        if (kc < 3) {
            #pragma unroll
            for (int jj = 0; jj < 2; ++jj) {
                const int m = w*2 + jj;
                gld16(src + (kc+1)*4096 + m*512 + lane*8, &Bs[buf^1][m*512]);
            }
        }
        f16x8 bfr[4][2];
        #pragma unroll
        for (int ft = 0; ft < 4; ++ft) {
            const int t = ft*16 + li;
            #pragma unroll
            for (int ks = 0; ks < 2; ++ks) {
                const int u = (4*ks + sub) ^ (t & 7);
                bfr[ft][ks] = *(const f16x8*)&Bs[buf][t*64 + u*8];
            }
        }
        #pragma unroll
        for (int ks = 0; ks < 2; ++ks) {
            #pragma unroll
            for (int fo = 0; fo < 4; ++fo) {
                const f16x8 a = *(const f16x8*)(fp + (size_t)(o0 + fo*16 + li)*256 + kc*64 + ks*32 + 8*sub);
                #pragma unroll
                for (int ft = 0; ft < 4; ++ft)
                    acc[fo][ft] = __builtin_amdgcn_mfma_f32_16x16x32_f16(a, bfr[ft][ks], acc[fo][ft], 0, 0, 0);
            }
        }
        __syncthreads();
    }

    // epilogue: wave-private LDS transpose, then 256B-contiguous nt stores
    #pragma unroll
    for (int fo = 0; fo < 4; ++fo) {
        float hv[4];
        #pragma unroll
        for (int r = 0; r < 4; ++r)
            hv[r] = h[b*256 + o0 + fo*16 + sub*4 + r];
        #pragma unroll
        for (int ft = 0; ft < 4; ++ft)
            #pragma unroll
            for (int r = 0; r < 4; ++r)
                Ts[w][sub*4 + r][ft*16 + li] = acc[fo][ft][r] + hv[r];
        #pragma unroll
        for (int it = 0; it < 4; ++it) {
            const int row = it*4 + sub;
            const f32x4 v = *(const f32x4*)&Ts[w][row][li*4];
            __builtin_nontemporal_store(v,
                (f32x4*)(out + ((size_t)(b*256 + o0 + fo*16 + row))*T_LEN + t0 + li*4));
        }
    }
}

// ---------------------------------------------------------------------------
extern "C" void kernel_launch(void* const* d_in, const int* in_sizes, int n_in,
                              void* d_out, int out_size, void* d_ws, size_t ws_size,
                              hipStream_t stream)
{
    const float* x       = (const float*)d_in[0];
    const float* cue     = (const float*)d_in[1];
    const float* gn_a_w  = (const float*)d_in[2];
    const float* gn_a_b  = (const float*)d_in[3];
    const float* gn_n_w  = (const float*)d_in[4];
    const float* gn_n_b  = (const float*)d_in[5];
    const float* f1g_w   = (const float*)d_in[6];
    const float* f1g_b   = (const float*)d_in[7];
    const float* f1b_w   = (const float*)d_in[8];
    const float* f1b_b   = (const float*)d_in[9];
    const float* ln1_w   = (const float*)d_in[10];
    const float* ln1_b   = (const float*)d_in[11];
    const float* conv1_w = (const float*)d_in[12];
    const float* cds_w   = (const float*)d_in[13];
    const float* f2g_w   = (const float*)d_in[14];
    const float* f2g_b   = (const float*)d_in[15];
    const float* f2b_w   = (const float*)d_in[16];
    const float* f2b_b   = (const float*)d_in[17];
    const float* ln2_w   = (const float*)d_in[18];
    const float* ln2_b   = (const float*)d_in[19];
    const float* conv2_w = (const float*)d_in[20];
    float* out = (float*)d_out;

    float* ws = (float*)d_ws;
    float*  sp   = ws;                       // 1,024,000
    float*  qp   = ws + 1024000;             // 1,024,000
    float*  G1   = ws + 2048000;             // 4,096
    float*  B1   = ws + 2052096;             // 4,096
    float*  CUE2 = ws + 2056192;             // 4,096
    float*  G2   = ws + 2060288;             // 2,048
    float*  a4   = ws + 2062336;             // 4,096
    float*  E    = ws + 2066432;             // 2,048
    float*  h    = ws + 2068480;             // 4,096
    float*  s2p  = ws + 2072576;             // 256,000
    float*  q2p  = ws + 2328576;             // 256,000
    ushort* Msf  = (ushort*)(ws + 2584576);  // 524,288 ush (262,144 f)
    ushort* Fsf  = (ushort*)(ws + 2846720);  // 1,048,576 ush (524,288 f)
    ushort* Xp   = (ushort*)(ws + 3371008);  // 65,536,000 ush
    // total ~ 36,139,008 floats ~= 144.6 MB

    kP1F<<<256 + NTT*NB, 256, 0, stream>>>(x, Xp, sp, qp,
        cue, f1g_w, f1g_b, f1b_w, f1b_b, cds_w, G1, B1, CUE2);

    kBM<<<NB, 256, 0, stream>>>(sp, qp, gn_a_w, gn_a_b, gn_n_w, gn_n_b,
                                G1, B1, ln1_w, ln1_b, CUE2,
                                f2g_w, f2g_b, f2b_w, f2b_b, conv1_w,
                                a4, G2, E, Msf);

    kC_gemm<<<dim3(NTB, NB), 256, 0, stream>>>(Xp, Msf, E, s2p, q2p);

    kD2_buildF<<<dim3(8, NB), 256, 0, stream>>>(s2p, q2p, ln2_w, ln2_b, E,
                                                a4, G2, conv1_w, conv2_w,
                                                Fsf, h);

    kE_gemm<<<dim3(NTT, NB), 256, 0, stream>>>(Xp, Fsf, h, out);
}